// Round 1
// baseline (1886.168 us; speedup 1.0000x reference)
//
#include <hip/hip_runtime.h>
#include <math.h>

#define EPS_YAT (1.0f/137.0f)

__device__ __forceinline__ float4 ld4(const float* p) { return *(const float4*)p; }

// Swizzled 64x64 LDS tile accessor: float4-slot index XORed with (row>>2).
// Makes strided-row reads (stride 4 rows) and same-row broadcast reads conflict-free.
__device__ __forceinline__ float* tptr(float* t, int row, int col) {
    int pc4 = ((col >> 2) ^ (row >> 2)) & 15;
    return t + row * 64 + (pc4 << 2) + (col & 3);
}

// ---- column norms of W [K,N] -> wn[N] ----
__global__ void colnorm_kernel(const float* __restrict__ W, float* __restrict__ wn,
                               int K, int N) {
    int n = blockIdx.x * 256 + threadIdx.x;
    if (n >= N) return;
    float s = 0.f;
    for (int k = 0; k < K; ++k) { float w = W[(size_t)k * N + n]; s += w * w; }
    wn[n] = s;
}

// ---- row norms of X [R,K] -> rn[R]; one wave per row, 4 rows/block ----
__global__ void rownorm_kernel(const float* __restrict__ X, float* __restrict__ rn, int K) {
    int wave = threadIdx.x >> 6;
    int lane = threadIdx.x & 63;
    int row = blockIdx.x * 4 + wave;
    const float* xr = X + (size_t)row * K;
    float s = 0.f;
    for (int k = lane * 4; k < K; k += 256) {
        float4 v = ld4(xr + k);
        s += v.x * v.x + v.y * v.y + v.z * v.z + v.w * v.w;
    }
    for (int off = 32; off; off >>= 1) s += __shfl_down(s, off);
    if (lane == 0) rn[row] = s;
}

// ---- q/k norms from qkv [B,T,3C]: qn/kn indexed [b*H+h][t] ----
__global__ void qknorm_kernel(const float* __restrict__ qkv, float* __restrict__ qn,
                              float* __restrict__ kn) {
    int gid = blockIdx.x * 256 + threadIdx.x;
    int lane = gid & 15;
    int idx = gid >> 4;                  // 0..98303
    int which = (idx >= 49152) ? 1 : 0;  // 0=q, 1=k
    int r = idx - which * 49152;
    int t = r & 1023;
    int bh = r >> 10;
    int h = bh % 12, b = bh / 12;
    const float* p = qkv + (size_t)(b * 1024 + t) * 2304 + which * 768 + h * 64 + lane * 4;
    float4 v = ld4(p);
    float s = v.x * v.x + v.y * v.y + v.z * v.z + v.w * v.w;
    s += __shfl_xor(s, 1, 16);
    s += __shfl_xor(s, 2, 16);
    s += __shfl_xor(s, 4, 16);
    s += __shfl_xor(s, 8, 16);
    if (lane == 0) (which ? kn : qn)[r] = s;
}

// ---- yat GEMM: out[m,n] = yat(A[m,:]·W[:,n]); 64x128 tile, 4x8 micro ----
__global__ __launch_bounds__(256)
void yat_gemm_kernel(const float* __restrict__ A, const float* __restrict__ W,
                     const float* __restrict__ bias, const float* __restrict__ xn,
                     const float* __restrict__ wn, const float* __restrict__ alphap,
                     const float Fdim, float* __restrict__ out,
                     const int M, const int N, const int K) {
    __shared__ float As[32][68];   // [k][m], padded
    __shared__ float Bs[32][132];  // [k][n], padded
    const int tid = threadIdx.x;
    const int m0 = blockIdx.y << 6;
    const int n0 = blockIdx.x << 7;
    const int r4 = (tid >> 4) << 2;
    const int c8 = (tid & 15) << 3;
    float acc[4][8] = {};
    const int la_m = tid >> 3;
    const int la_k = (tid & 7) << 2;
    const int lb_r = tid >> 5;
    const int lb_c = (tid & 31) << 2;
    for (int k0 = 0; k0 < K; k0 += 32) {
        __syncthreads();
        #pragma unroll
        for (int l = 0; l < 2; ++l) {
            int m = la_m + (l << 5);
            float4 v = ld4(A + (size_t)(m0 + m) * K + k0 + la_k);
            As[la_k + 0][m] = v.x;
            As[la_k + 1][m] = v.y;
            As[la_k + 2][m] = v.z;
            As[la_k + 3][m] = v.w;
        }
        #pragma unroll
        for (int l = 0; l < 4; ++l) {
            int kk = lb_r + (l << 3);
            *(float4*)&Bs[kk][lb_c] = ld4(W + (size_t)(k0 + kk) * N + n0 + lb_c);
        }
        __syncthreads();
        #pragma unroll
        for (int kk = 0; kk < 32; ++kk) {
            float4 av  = *(const float4*)&As[kk][r4];
            float4 bv0 = *(const float4*)&Bs[kk][c8];
            float4 bv1 = *(const float4*)&Bs[kk][c8 + 4];
            float aa[4] = {av.x, av.y, av.z, av.w};
            float bb[8] = {bv0.x, bv0.y, bv0.z, bv0.w, bv1.x, bv1.y, bv1.z, bv1.w};
            #pragma unroll
            for (int i = 0; i < 4; ++i)
                #pragma unroll
                for (int j = 0; j < 8; ++j)
                    acc[i][j] += aa[i] * bb[j];
        }
    }
    const float scale = powf(sqrtf(Fdim) / log1pf(Fdim), *alphap);
    #pragma unroll
    for (int i = 0; i < 4; ++i) {
        const int m = m0 + r4 + i;
        const float xnm = xn[m];
        float o[8];
        #pragma unroll
        for (int j = 0; j < 8; ++j) {
            const int n = n0 + c8 + j;
            float d = acc[i][j];
            float den = xnm + wn[n] - 2.f * d + EPS_YAT;
            o[j] = (d * d / den + bias[n]) * scale;
        }
        float* op = out + (size_t)m * N + n0 + c8;
        *(float4*)op       = make_float4(o[0], o[1], o[2], o[3]);
        *(float4*)(op + 4) = make_float4(o[4], o[5], o[6], o[7]);
    }
}

// ---- flash attention with yat score; 64 q-rows per block ----
__global__ __launch_bounds__(256)
void yat_flash_kernel(const float* __restrict__ qkv, const float* __restrict__ qn,
                      const float* __restrict__ kn, float* __restrict__ out) {
    __shared__ float Qs[64 * 64], Ks[64 * 64], Vs[64 * 64], Ps[64 * 64];
    __shared__ float qns[64], kns[64];
    const int tid = threadIdx.x;
    const int qt = blockIdx.x;   // 0..15
    const int bh = blockIdx.y;   // 0..47
    const int h = bh % 12, b = bh / 12;
    const int lr = tid >> 4;
    const int lc = (tid & 15) << 2;
    const size_t base = (size_t)b * 1024 * 2304 + h * 64;
    #pragma unroll
    for (int l = 0; l < 4; ++l) {
        int row = lr + l * 16;
        int t = (qt << 6) + row;
        *(float4*)tptr(Qs, row, lc) = ld4(qkv + base + (size_t)t * 2304 + lc);
    }
    if (tid < 64) qns[tid] = qn[bh * 1024 + (qt << 6) + tid];
    const int r = tid >> 4, c = tid & 15;
    const int r4 = r << 2, c4 = c << 2;
    float acc[4][4] = {};
    float mrow[4] = {-3e38f, -3e38f, -3e38f, -3e38f};
    float lrow[4] = {0.f, 0.f, 0.f, 0.f};

    for (int kt = 0; kt <= qt; ++kt) {
        __syncthreads();
        #pragma unroll
        for (int l = 0; l < 4; ++l) {
            int row = lr + l * 16;
            int t = (kt << 6) + row;
            *(float4*)tptr(Ks, row, lc) = ld4(qkv + base + 768  + (size_t)t * 2304 + lc);
            *(float4*)tptr(Vs, row, lc) = ld4(qkv + base + 1536 + (size_t)t * 2304 + lc);
        }
        if (tid < 64) kns[tid] = kn[bh * 1024 + (kt << 6) + tid];
        __syncthreads();

        // S = Q K^T (4x4 micro over 64-d)
        float s[4][4] = {};
        #pragma unroll
        for (int d = 0; d < 64; d += 4) {
            float4 aR[4], bR[4];
            #pragma unroll
            for (int i = 0; i < 4; ++i) aR[i] = *(const float4*)tptr(Qs, r4 + i, d);
            #pragma unroll
            for (int j = 0; j < 4; ++j) bR[j] = *(const float4*)tptr(Ks, c4 + j, d);
            #pragma unroll
            for (int i = 0; i < 4; ++i)
                #pragma unroll
                for (int j = 0; j < 4; ++j)
                    s[i][j] += aR[i].x * bR[j].x + aR[i].y * bR[j].y +
                               aR[i].z * bR[j].z + aR[i].w * bR[j].w;
        }
        // yat score + causal mask + online softmax
        float mt[4];
        #pragma unroll
        for (int i = 0; i < 4; ++i) {
            int ig = (qt << 6) + r4 + i;
            float qni = qns[r4 + i];
            float mm = -3e38f;
            #pragma unroll
            for (int j = 0; j < 4; ++j) {
                int jg = (kt << 6) + c4 + j;
                float sv = s[i][j] * 0.125f;
                float num = sv * sv;
                float den = qni + kns[c4 + j] - 2.f * sv + EPS_YAT;
                float sc = (jg <= ig) ? (num / den) : -3e38f;
                s[i][j] = sc;
                mm = fmaxf(mm, sc);
            }
            mt[i] = mm;
        }
        #pragma unroll
        for (int i = 0; i < 4; ++i) {
            float mm = mt[i];
            mm = fmaxf(mm, __shfl_xor(mm, 8, 16));
            mm = fmaxf(mm, __shfl_xor(mm, 4, 16));
            mm = fmaxf(mm, __shfl_xor(mm, 2, 16));
            mm = fmaxf(mm, __shfl_xor(mm, 1, 16));
            mt[i] = mm;
        }
        #pragma unroll
        for (int i = 0; i < 4; ++i) {
            float mnew = fmaxf(mrow[i], mt[i]);
            float al = __expf(mrow[i] - mnew);
            mrow[i] = mnew;
            float rs = 0.f;
            #pragma unroll
            for (int j = 0; j < 4; ++j) {
                float p = __expf(s[i][j] - mnew);  // masked -> exp(-huge) = 0
                s[i][j] = p;
                rs += p;
            }
            rs += __shfl_xor(rs, 8, 16);
            rs += __shfl_xor(rs, 4, 16);
            rs += __shfl_xor(rs, 2, 16);
            rs += __shfl_xor(rs, 1, 16);
            lrow[i] = lrow[i] * al + rs;
            #pragma unroll
            for (int j = 0; j < 4; ++j) acc[i][j] *= al;
            *(float4*)tptr(Ps, r4 + i, c4) = make_float4(s[i][0], s[i][1], s[i][2], s[i][3]);
        }
        __syncthreads();
        // O += P V
        #pragma unroll
        for (int jj = 0; jj < 64; jj += 4) {
            float4 pR[4], vR[4];
            #pragma unroll
            for (int i = 0; i < 4; ++i) pR[i] = *(const float4*)tptr(Ps, r4 + i, jj);
            #pragma unroll
            for (int t2 = 0; t2 < 4; ++t2) vR[t2] = *(const float4*)tptr(Vs, jj + t2, c4);
            #pragma unroll
            for (int i = 0; i < 4; ++i) {
                acc[i][0] += pR[i].x * vR[0].x + pR[i].y * vR[1].x + pR[i].z * vR[2].x + pR[i].w * vR[3].x;
                acc[i][1] += pR[i].x * vR[0].y + pR[i].y * vR[1].y + pR[i].z * vR[2].y + pR[i].w * vR[3].y;
                acc[i][2] += pR[i].x * vR[0].z + pR[i].y * vR[1].z + pR[i].z * vR[2].z + pR[i].w * vR[3].z;
                acc[i][3] += pR[i].x * vR[0].w + pR[i].y * vR[1].w + pR[i].z * vR[2].w + pR[i].w * vR[3].w;
            }
        }
    }
    #pragma unroll
    for (int i = 0; i < 4; ++i) {
        int t = (qt << 6) + r4 + i;
        float inv = 1.f / lrow[i];
        *(float4*)(out + (size_t)(b * 1024 + t) * 768 + h * 64 + c4) =
            make_float4(acc[i][0] * inv, acc[i][1] * inv, acc[i][2] * inv, acc[i][3] * inv);
    }
}

extern "C" void kernel_launch(void* const* d_in, const int* in_sizes, int n_in,
                              void* d_out, int out_size, void* d_ws, size_t ws_size,
                              hipStream_t stream) {
    const float* x          = (const float*)d_in[0];
    // d_in[1] = mask (causal, known structure — unused)
    const float* W_attn     = (const float*)d_in[2];
    const float* b_attn     = (const float*)d_in[3];
    const float* alpha_attn = (const float*)d_in[4];
    const float* W_proj     = (const float*)d_in[5];
    const float* b_proj     = (const float*)d_in[6];
    const float* alpha_proj = (const float*)d_in[7];

    float* ws       = (float*)d_ws;
    float* qkv      = ws;                 // 4*1024*2304 = 9437184
    float* attn_out = ws + 9437184;       // 4*1024*768  = 3145728
    float* xn       = ws + 12582912;      // 4096
    float* an       = ws + 12587008;      // 4096
    float* wn_attn  = ws + 12591104;      // 2304
    float* wn_proj  = ws + 12593408;      // 768
    float* qn       = ws + 12594176;      // 49152
    float* kn       = ws + 12643328;      // 49152  (end: 12692480 floats ~50.8 MB)

    colnorm_kernel<<<9, 256, 0, stream>>>(W_attn, wn_attn, 768, 2304);
    colnorm_kernel<<<3, 256, 0, stream>>>(W_proj, wn_proj, 768, 768);
    rownorm_kernel<<<1024, 256, 0, stream>>>(x, xn, 768);
    yat_gemm_kernel<<<dim3(18, 64), 256, 0, stream>>>(
        x, W_attn, b_attn, xn, wn_attn, alpha_attn, 2304.f, qkv, 4096, 2304, 768);
    qknorm_kernel<<<6144, 256, 0, stream>>>(qkv, qn, kn);
    yat_flash_kernel<<<dim3(16, 48), 256, 0, stream>>>(qkv, qn, kn, attn_out);
    rownorm_kernel<<<1024, 256, 0, stream>>>(attn_out, an, 768);
    yat_gemm_kernel<<<dim3(6, 64), 256, 0, stream>>>(
        attn_out, W_proj, b_proj, an, wn_proj, alpha_proj, 768.f, (float*)d_out, 4096, 768, 768);
}